// Round 12
// baseline (205.772 us; speedup 1.0000x reference)
//
#include <hip/hip_runtime.h>
#include <hip/hip_fp16.h>

#define N_NODES 50000
#define N_EDGES 1600000
#define IN_DIM 256
#define OUT_DIM 128
#define NEG_SLOPE 0.01f

// ---- geometry: coarse sorts DIRECTLY by 32-row gather bins ----
#define BIN_SH    5
#define BIN_ROWS  32
#define NCLASS    ((N_NODES + BIN_ROWS - 1) / BIN_ROWS)  // 1563 bins
#define TSTRIDE   (NCLASS + 1)                           // 1564 (bounds table stride)
#define CAPG      1536                                   // gather LDS cap (+16 sigma)
#define NCLS      256                                    // gather sort classes

#define SCAT_BLOCKS 256
#define EPB_S (N_EDGES / SCAT_BLOCKS)      // 6250
#define SCAT_ITERS ((EPB_S + 511) / 512)   // 13

#define BM 128
#define GEMM_BLOCKS ((N_NODES + BM - 1) / BM)  // 391
#define PREP_BLOCKS (SCAT_BLOCKS + GEMM_BLOCKS)

typedef _Float16 f16x8 __attribute__((ext_vector_type(8)));
typedef float    f32x4 __attribute__((ext_vector_type(4)));
typedef float    f32x8 __attribute__((ext_vector_type(8)));

__device__ __forceinline__ float lrelu(float v) {
    return v >= 0.f ? v : NEG_SLOPE * v;
}

#define CVT16(lo, hi) do { \
    lo[0]=(_Float16)xr[0].x; lo[1]=(_Float16)xr[0].y; lo[2]=(_Float16)xr[0].z; lo[3]=(_Float16)xr[0].w; \
    lo[4]=(_Float16)xr[1].x; lo[5]=(_Float16)xr[1].y; lo[6]=(_Float16)xr[1].z; lo[7]=(_Float16)xr[1].w; \
    hi[0]=(_Float16)xr[2].x; hi[1]=(_Float16)xr[2].y; hi[2]=(_Float16)xr[2].z; hi[3]=(_Float16)xr[2].w; \
    hi[4]=(_Float16)xr[3].x; hi[5]=(_Float16)xr[3].y; hi[6]=(_Float16)xr[3].z; hi[7]=(_Float16)xr[3].w; \
} while (0)

// ---------------------------------------------------------------------------
// Dispatch 1 "prep" (647 blocks, 512 thr, 61.1 KB smem union):
//   blocks 0..255   : coarse scatter -- LDS counting sort by the 1563
//                     32-row GATHER bins directly (fine-scatter kernel is
//                     DELETED; the gather assembles bins from the per-
//                     (block,bin) runs). Dense per-block write + full
//                     1564-entry bounds table per block.
//   blocks 256..646 : gemm h = x@W (self-staged W halves, MFMA). Unchanged.
// Record: { row<<16 | col , val_bits }.
// ---------------------------------------------------------------------------
__global__ __launch_bounds__(512, 2) void prep(const int* __restrict__ rows,
                                               const int* __restrict__ cols,
                                               const float* __restrict__ vals,
                                               const float* __restrict__ x,
                                               const float* __restrict__ w,
                                               int* __restrict__ cstartarr,
                                               int2* __restrict__ cbuf,
                                               __half* __restrict__ h) {
    __shared__ __attribute__((aligned(16))) char smem[62560];
    const int bid = blockIdx.x;
    const int t   = threadIdx.x;

    if (bid < SCAT_BLOCKS) {
        // ================= coarse scatter role =================
        int2* lsort  = (int2*)smem;                 // 6250 rec = 50,000 B
        int*  hist   = (int*)(smem + 50000);        // 1563 * 4 = 6252 B
        int*  cstart = (int*)(smem + 56256);        // 6252 B
        int*  wsum8  = (int*)(smem + 62512);        // 8 * 4
        const int lane  = t & 63;
        const int wv    = t >> 6;                   // 0..7
        const int blk   = bid;
        const int ebase = blk * EPB_S;

        for (int m = t; m < NCLASS; m += 512) hist[m] = 0;
        __syncthreads();

        // pass 1: histogram by 32-row bin (rows cached in regs)
        int myr[SCAT_ITERS];
#pragma unroll
        for (int k = 0; k < SCAT_ITERS; ++k) {
            const int i = k * 512 + t;
            myr[k] = -1;
            if (i < EPB_S) {
                myr[k] = rows[ebase + i];
                atomicAdd(&hist[myr[k] >> BIN_SH], 1);
            }
        }
        __syncthreads();

        // exclusive scan over 1563 classes: 4/thread, 8-wave shfl + combine
        {
            const int base = t << 2;
            const int v0 = (base + 0 < NCLASS) ? hist[base + 0] : 0;
            const int v1 = (base + 1 < NCLASS) ? hist[base + 1] : 0;
            const int v2 = (base + 2 < NCLASS) ? hist[base + 2] : 0;
            const int v3 = (base + 3 < NCLASS) ? hist[base + 3] : 0;
            const int sum = v0 + v1 + v2 + v3;
            int s = sum;
#pragma unroll
            for (int off = 1; off < 64; off <<= 1) {
                const int u = __shfl_up(s, off);
                if (lane >= off) s += u;
            }
            if (lane == 63) wsum8[wv] = s;
            __syncthreads();
            if (t == 0) {
                int a = 0;
#pragma unroll
                for (int i = 0; i < 8; ++i) { const int c = wsum8[i]; wsum8[i] = a; a += c; }
            }
            __syncthreads();
            const int excl = s - sum + wsum8[wv];
            if (base + 0 < NCLASS) { cstart[base + 0] = excl;               hist[base + 0] = excl; }
            if (base + 1 < NCLASS) { cstart[base + 1] = excl + v0;          hist[base + 1] = excl + v0; }
            if (base + 2 < NCLASS) { cstart[base + 2] = excl + v0 + v1;     hist[base + 2] = excl + v0 + v1; }
            if (base + 3 < NCLASS) { cstart[base + 3] = excl + v0 + v1 + v2; hist[base + 3] = excl + v0 + v1 + v2; }
        }
        __syncthreads();

        // pass 2: place into LDS sorted order (cols/vals read coalesced)
#pragma unroll
        for (int k = 0; k < SCAT_ITERS; ++k) {
            const int i = k * 512 + t;
            if (i < EPB_S) {
                const int e = ebase + i;
                const int r = myr[k];
                const int pos = atomicAdd(&hist[r >> BIN_SH], 1);
                lsort[pos] = make_int2((int)(((unsigned)r << 16) | (unsigned)cols[e]),
                                       __float_as_int(vals[e]));
            }
        }
        __syncthreads();

        // pass 3: dense coalesced write-out + bounds table
        {
            const int4* src = (const int4*)lsort;
            int4* dst = (int4*)(cbuf + (size_t)blk * EPB_S);
            for (int i = t; i < EPB_S / 2; i += 512) dst[i] = src[i];
        }
        for (int m = t; m < NCLASS; m += 512) cstartarr[blk * TSTRIDE + m] = cstart[m];
        if (t == 0) cstartarr[blk * TSTRIDE + NCLASS] = EPB_S;
        return;
    }

    // ================= gemm role (t<256 active) =================
    f16x8* wt8h = (f16x8*)smem;                    // 32 KB half-W frag
    f16x8* xs8  = (f16x8*)(smem + 32768);          // 16 KB x double-buffer
    const int a256 = (t < 256);
    const int lane = t & 63;
    const int wv   = t >> 6;
    const int row0 = (bid - SCAT_BLOCKS) * BM;

    const int srow = t >> 1;
    const int skh  = t & 1;
    const int grow = row0 + srow;
    const bool rv  = a256 && (grow < N_NODES);
    const float* xp = x + (size_t)(rv ? grow : 0) * IN_DIM + skh * 16;

    float4 xr[4];
    if (a256) {
#pragma unroll
        for (int i = 0; i < 4; ++i)
            xr[i] = rv ? ((const float4*)xp)[i] : make_float4(0.f, 0.f, 0.f, 0.f);
        f16x8 lo, hi;
        CVT16(lo, hi);
        xs8[(0 * 4 + skh * 2 + 0) * 128 + srow] = lo;
        xs8[(0 * 4 + skh * 2 + 1) * 128 + srow] = hi;
    }
    __syncthreads();

    f32x4 acc[2][8];
#pragma unroll
    for (int mf = 0; mf < 2; ++mf)
#pragma unroll
        for (int nf = 0; nf < 8; ++nf) acc[mf][nf] = (f32x4){0.f, 0.f, 0.f, 0.f};

    const int kgl = lane >> 4;
    const int l15 = lane & 15;
    const int mb  = (wv << 5) + l15;

#pragma unroll
    for (int H = 0; H < 2; ++H) {
        if (a256) {
#pragma unroll
            for (int itr = 0; itr < 8; ++itr) {
                const int e  = itr * 2048 + t * 8;
                const int kl = e >> 7;
                const int n0 = e & 127;
                const float4 a4 = *(const float4*)(w + (size_t)((H << 7) + kl) * 128 + n0);
                const float4 b4 = *(const float4*)(w + (size_t)((H << 7) + kl) * 128 + n0 + 4);
                __half* d = (__half*)wt8h + (size_t)(((kl >> 3) << 7) + n0) * 8 + (kl & 7);
                d[0]  = __float2half(a4.x);
                d[8]  = __float2half(a4.y);
                d[16] = __float2half(a4.z);
                d[24] = __float2half(a4.w);
                d[32] = __float2half(b4.x);
                d[40] = __float2half(b4.y);
                d[48] = __float2half(b4.z);
                d[56] = __float2half(b4.w);
            }
        }
        __syncthreads();

#pragma unroll
        for (int ksl = 0; ksl < 4; ++ksl) {
            const int ks  = H * 4 + ksl;
            const int cur = ks & 1;
            if (a256 && ks < 7) {
#pragma unroll
                for (int i = 0; i < 4; ++i)
                    xr[i] = rv ? ((const float4*)(xp + (ks + 1) * 32))[i]
                               : make_float4(0.f, 0.f, 0.f, 0.f);
            }
            if (a256) {
                const f16x8 b0 = xs8[(cur * 4 + kgl) * 128 + mb];
                const f16x8 b1 = xs8[(cur * 4 + kgl) * 128 + mb + 16];
                const int abase = ((ksl * 4 + kgl) << 7) + l15;
#pragma unroll
                for (int nf = 0; nf < 8; ++nf) {
                    const f16x8 a = wt8h[abase + (nf << 4)];
                    acc[0][nf] = __builtin_amdgcn_mfma_f32_16x16x32_f16(a, b0, acc[0][nf], 0, 0, 0);
                    acc[1][nf] = __builtin_amdgcn_mfma_f32_16x16x32_f16(a, b1, acc[1][nf], 0, 0, 0);
                }
            }
            if (a256 && ks < 7) {
                f16x8 lo, hi;
                CVT16(lo, hi);
                xs8[((cur ^ 1) * 4 + skh * 2 + 0) * 128 + srow] = lo;
                xs8[((cur ^ 1) * 4 + skh * 2 + 1) * 128 + srow] = hi;
            }
            __syncthreads();
        }
    }

    if (a256) {
        const int rg = lane >> 4;
#pragma unroll
        for (int mf = 0; mf < 2; ++mf) {
            const int m = row0 + (wv << 5) + (mf << 4) + l15;
            if (m < N_NODES) {
                __half* hp = h + (size_t)m * OUT_DIM + (rg << 2);
#pragma unroll
                for (int nf = 0; nf < 8; ++nf) {
                    union { ushort4 u; __half f[4]; } o;
                    o.f[0] = __float2half(acc[mf][nf][0]);
                    o.f[1] = __float2half(acc[mf][nf][1]);
                    o.f[2] = __float2half(acc[mf][nf][2]);
                    o.f[3] = __float2half(acc[mf][nf][3]);
                    *(ushort4*)(hp + (nf << 4)) = o.u;
                }
            }
        }
    }
}

// ---------------------------------------------------------------------------
// Dispatch 2: FUSED assemble+sort+gather. One block per 32-row bin (1563
// blocks, 256 thr, ~26 KB LDS -> 6 blocks/CU, 24 waves = 75% theoretical;
// the round-11-proven residency regime). Thread t owns coarse block t's
// run for this bin: reads bounds (one 8 B pair), shfl-scans lengths ->
// urec offsets, copies its ~4 records from L3-hot cbuf while histogramming
// by (lrow, col-slice). Then 256-class sort LDS->LDS and the round-11
// register gather (4 waves x 8 rows in pairs). No fine-scatter kernel, no
// ebuf, no caps except CAPG (+16 sigma; in-kernel slow-path fallback).
// ---------------------------------------------------------------------------
#define GCLS(K) ((((K) >> 16) & 31) << 3 | (((K) & 0xFFFF) >> 13))

__global__ __launch_bounds__(256) void sort_gather(const int* __restrict__ cstartarr,
                                                   const int2* __restrict__ cbuf,
                                                   const __half* __restrict__ h,
                                                   float* __restrict__ out) {
    __shared__ int2 urec[CAPG];            // 12 KB raw records
    __shared__ int2 srec[CAPG];            // 12 KB sorted records
    __shared__ int  hist[NCLS];            // 1 KB
    __shared__ int  rowoff_l[BIN_ROWS + 1];
    __shared__ int  wsum[4];
    __shared__ int  cnt_sh;

    const int t    = threadIdx.x;          // 0..255
    const int bin  = blockIdx.x;
    const int wv   = t >> 6;               // 0..3
    const int lane = t & 63;

    hist[t] = 0;

    // ---- bounds: thread t owns coarse block t's run ----
    const int s0 = cstartarr[t * TSTRIDE + bin];
    const int c  = cstartarr[t * TSTRIDE + bin + 1] - s0;

    // ---- shfl-scan run lengths -> urec offsets + total ----
    int s = c;
#pragma unroll
    for (int off = 1; off < 64; off <<= 1) {
        const int u = __shfl_up(s, off);
        if (lane >= off) s += u;
    }
    if (lane == 63) wsum[wv] = s;
    __syncthreads();
    if (t == 0) {
        int a = 0;
#pragma unroll
        for (int i = 0; i < 4; ++i) { const int q = wsum[i]; wsum[i] = a; a += q; }
        cnt_sh = a;
    }
    __syncthreads();
    const int excl = s - c + wsum[wv];
    const int cnt  = cnt_sh;

    if (cnt <= CAPG) {
        // ---- stage own run into urec + class histogram ----
        const int2* src = cbuf + (size_t)t * EPB_S + s0;
        for (int i = 0; i < c; ++i) {
            const int2 r = src[i];
            urec[excl + i] = r;
            atomicAdd(&hist[GCLS(r.x)], 1);
        }
        __syncthreads();

        // ---- 256-class scan (4-wave shfl + combine) ----
        {
            const int v = hist[t];
            int ss = v;
#pragma unroll
            for (int off = 1; off < 64; off <<= 1) {
                const int u = __shfl_up(ss, off);
                if (lane >= off) ss += u;
            }
            if (lane == 63) wsum[wv] = ss;
            __syncthreads();
            if (t == 0) {
                int a = 0;
#pragma unroll
                for (int i = 0; i < 4; ++i) { const int q = wsum[i]; wsum[i] = a; a += q; }
            }
            __syncthreads();
            hist[t] = ss + wsum[wv] - v;   // exclusive prefix -> sort cursor
        }
        __syncthreads();
        if (t < BIN_ROWS) rowoff_l[t] = hist[t << 3];
        if (t == 0) rowoff_l[BIN_ROWS] = cnt;
        __syncthreads();

        // ---- counting sort LDS -> LDS ----
        for (int i = t; i < cnt; i += 256) {
            const int2 r = urec[i];
            const int pos = atomicAdd(&hist[GCLS(r.x)], 1);
            srec[pos] = r;
        }
        __syncthreads();

        // ---- gather: 4 waves x 8 rows, pairs (round-11 proven shape) ----
        const int grp = lane >> 4;
        const int gl  = lane & 15;

        for (int pp = 0; pp < 4; ++pp) {
            const int lr0 = (wv << 3) + 2 * pp;
            const int lr1 = lr0 + 1;
            const int b0 = rowoff_l[lr0], e0 = rowoff_l[lr0 + 1];
            const int b1 = rowoff_l[lr1], e1 = rowoff_l[lr1 + 1];
            const int n0 = e0 - b0, n1 = e1 - b1;
            const int nmax = n0 > n1 ? n0 : n1;
            const int iters = (nmax + 3) >> 2;

            f32x8 a0 = (f32x8){0.f,0.f,0.f,0.f,0.f,0.f,0.f,0.f};
            f32x8 a1 = (f32x8){0.f,0.f,0.f,0.f,0.f,0.f,0.f,0.f};

            for (int it = 0; it < iters; ++it) {
                const int i0 = b0 + (it << 2) + grp;
                const int i1 = b1 + (it << 2) + grp;
                const bool v0i = i0 < e0;
                const bool v1i = i1 < e1;
                const int2 rA = srec[v0i ? i0 : 0];
                const int2 rB = srec[v1i ? i1 : 0];
                const float vA = v0i ? __int_as_float(rA.y) : 0.f;
                const float vB = v1i ? __int_as_float(rB.y) : 0.f;
                const f16x8 hA = *(const f16x8*)(h + (size_t)(rA.x & 0xFFFF) * OUT_DIM + (gl << 3));
                const f16x8 hB = *(const f16x8*)(h + (size_t)(rB.x & 0xFFFF) * OUT_DIM + (gl << 3));
#pragma unroll
                for (int j = 0; j < 8; ++j) {
                    a0[j] += vA * (float)hA[j];
                    a1[j] += vB * (float)hB[j];
                }
            }

#pragma unroll
            for (int j = 0; j < 8; ++j) {
                float x0 = a0[j], x1 = a1[j];
                x0 += __shfl_xor(x0, 16); x0 += __shfl_xor(x0, 32);
                x1 += __shfl_xor(x1, 16); x1 += __shfl_xor(x1, 32);
                a0[j] = x0; a1[j] = x1;
            }

            const int lrow = (grp & 2) ? lr1 : lr0;
            const int grow = (bin << BIN_SH) + lrow;
            float q[4];
#pragma unroll
            for (int k = 0; k < 4; ++k) {
                const float lo = (grp & 2) ? a1[k]     : a0[k];
                const float hi = (grp & 2) ? a1[k + 4] : a0[k + 4];
                q[k] = lrelu((grp & 1) ? hi : lo);
            }
            if (grow < N_NODES) {
                float4 o = make_float4(q[0], q[1], q[2], q[3]);
                *(float4*)(out + (size_t)grow * OUT_DIM + (gl << 3) + ((grp & 1) << 2)) = o;
            }
        }
    } else {
        // ---- slow-path fallback (cnt > +16 sigma; statistically unreachable)
        //      wave scans ALL runs from global, filtering its row pair ----
        for (int pp = 0; pp < 4; ++pp) {
            const int lr0 = (wv << 3) + 2 * pp;
            const int lr1 = lr0 + 1;
            float2 a0 = make_float2(0.f, 0.f);
            float2 a1 = make_float2(0.f, 0.f);
            for (int b = 0; b < 256; ++b) {
                const int sb = cstartarr[b * TSTRIDE + bin];
                const int eb = cstartarr[b * TSTRIDE + bin + 1];
                for (int e = sb; e < eb; ++e) {
                    const int2 rec = cbuf[(size_t)b * EPB_S + e];
                    const int lr = (rec.x >> 16) & 31;
                    if (lr == lr0 || lr == lr1) {
                        const float v = __int_as_float(rec.y);
                        const float2 m = __half22float2(((const __half2*)(h + (size_t)(rec.x & 0xFFFF) * OUT_DIM))[lane]);
                        if (lr == lr0) { a0.x += v * m.x; a0.y += v * m.y; }
                        else           { a1.x += v * m.x; a1.y += v * m.y; }
                    }
                }
            }
            const int g0 = (bin << BIN_SH) + lr0;
            const int g1 = (bin << BIN_SH) + lr1;
            if (g0 < N_NODES) {
                float2 o = make_float2(lrelu(a0.x), lrelu(a0.y));
                ((float2*)(out + (size_t)g0 * OUT_DIM))[lane] = o;
            }
            if (g1 < N_NODES) {
                float2 o = make_float2(lrelu(a1.x), lrelu(a1.y));
                ((float2*)(out + (size_t)g1 * OUT_DIM))[lane] = o;
            }
        }
    }
}

// ---------------------------------------------------------------------------
// Launch: TWO dispatches, no memsets, no overflow buffers.
// prep (coarse-by-bin || gemm) -> sort_gather (assemble+sort+gather).
// ---------------------------------------------------------------------------
extern "C" void kernel_launch(void* const* d_in, const int* in_sizes, int n_in,
                              void* d_out, int out_size, void* d_ws, size_t ws_size,
                              hipStream_t stream) {
    const float* x    = (const float*)d_in[0];
    const float* w    = (const float*)d_in[1];
    const float* vals = (const float*)d_in[2];
    const int*   rows = (const int*)d_in[3];
    const int*   cols = (const int*)d_in[4];
    float* out = (float*)d_out;

    char* ws = (char*)d_ws;
    size_t off = 0;
    auto alloc = [&](size_t bytes) {
        void* p = ws + off;
        off = (off + bytes + 255) & ~(size_t)255;
        return p;
    };
    int2*   cbuf     = (int2*)  alloc((size_t)N_EDGES * sizeof(int2));               // 12.8 MB
    __half* h        = (__half*)alloc((size_t)N_NODES * OUT_DIM * sizeof(__half));   // 12.8 MB
    int*    cstartarr= (int*)   alloc((size_t)SCAT_BLOCKS * TSTRIDE * sizeof(int));  // 1.6 MB

    prep<<<PREP_BLOCKS, 512, 0, stream>>>(rows, cols, vals, x, w, cstartarr, cbuf, h);
    sort_gather<<<NCLASS, 256, 0, stream>>>(cstartarr, cbuf, h, out);
}

// Round 13
// 193.295 us; speedup vs baseline: 1.0646x; 1.0646x over previous
//
#include <hip/hip_runtime.h>
#include <hip/hip_fp16.h>

#define N_NODES 50000
#define N_EDGES 1600000
#define IN_DIM 256
#define OUT_DIM 128
#define NEG_SLOPE 0.01f

// ---- geometry (round-11, best verified: 192.5 us) ----
#define SB_SH     10
#define NSB       49                       // super-bins of 1024 rows
#define BIN_SH    4
#define BIN_ROWS  16                       // 16-row fine bins
#define NBIN_PAD  (NSB * 64)               // 3136 bins
#define NPART     16                       // fine parts per super-bin
#define ECAP      2560                     // records per (sb,part) slab (+11 sigma)
#define SEGP      96                       // per-(bin,part) clamp (+11 sigma)
#define CAPG      (NPART * SEGP)           // 1536 gather LDS records (12 KB)
#define OVF_CAP   65536

#define SCAT_BLOCKS 256
#define EPB_S (N_EDGES / SCAT_BLOCKS)      // 6250
#define SCAT_ITERS ((EPB_S + 511) / 512)   // 13

#define BM 128
#define GEMM_BLOCKS ((N_NODES + BM - 1) / BM)  // 391
#define PREP_BLOCKS (SCAT_BLOCKS + GEMM_BLOCKS + 1)

typedef _Float16 f16x8 __attribute__((ext_vector_type(8)));
typedef float    f32x4 __attribute__((ext_vector_type(4)));
typedef float    f32x8 __attribute__((ext_vector_type(8)));

__device__ __forceinline__ float lrelu(float v) {
    return v >= 0.f ? v : NEG_SLOPE * v;
}

// ---------------------------------------------------------------------------
// Dispatch 1 "prep": round-11 structure, ONE change -- the gemm role now
// uses ALL 8 WAVES (was t<256: half of every gemm block idle, a fusion
// artifact since round 9). Wave wv owns 16 output rows (one B-fragment,
// acc[8]); all 512 threads stage x (1 f16x8 each) and W (4 iters). Same
// MFMA count per block at 2x issue width.
//   blocks 0..255   : coarse scatter (LDS sort by super-bin, dense write)
//   blocks 256..646 : gemm h = x@W
//   block  647      : zero ovfcnt
// Record: { row<<16 | col , val_bits }.
// ---------------------------------------------------------------------------
__global__ __launch_bounds__(512, 2) void prep(const int* __restrict__ rows,
                                               const int* __restrict__ cols,
                                               const float* __restrict__ vals,
                                               const float* __restrict__ x,
                                               const float* __restrict__ w,
                                               int* __restrict__ cstartarr,
                                               int* __restrict__ ovfcnt,
                                               int2* __restrict__ cbuf,
                                               __half* __restrict__ h) {
    __shared__ __attribute__((aligned(16))) char smem[50432];
    const int bid = blockIdx.x;
    const int t   = threadIdx.x;

    if (bid >= SCAT_BLOCKS + GEMM_BLOCKS) {        // zero-block
        if (t == 0) *ovfcnt = 0;
        return;
    }

    if (bid < SCAT_BLOCKS) {
        // ================= coarse scatter role (unchanged r11) =================
        int2* lsort  = (int2*)smem;                // 6250 rec = 50,000 B
        int*  hist   = (int*)(smem + 50000);       // 49
        int*  cstart = (int*)(smem + 50200);       // 49
        const int lane  = t & 63;
        const int blk   = bid;
        const int ebase = blk * EPB_S;

        if (t < NSB) hist[t] = 0;
        __syncthreads();

        int myr[SCAT_ITERS];
#pragma unroll
        for (int k = 0; k < SCAT_ITERS; ++k) {
            const int i = k * 512 + t;
            myr[k] = -1;
            if (i < EPB_S) {
                myr[k] = rows[ebase + i];
                atomicAdd(&hist[myr[k] >> SB_SH], 1);
            }
        }
        __syncthreads();

        if (t < 64) {                              // scan 49 sbins (wave 0)
            const int v = (t < NSB) ? hist[t] : 0;
            int s = v;
#pragma unroll
            for (int off = 1; off < 64; off <<= 1) {
                const int u = __shfl_up(s, off);
                if (lane >= off) s += u;
            }
            if (t < NSB) { cstart[t] = s - v; hist[t] = s - v; }
        }
        __syncthreads();

#pragma unroll
        for (int k = 0; k < SCAT_ITERS; ++k) {
            const int i = k * 512 + t;
            if (i < EPB_S) {
                const int e = ebase + i;
                const int r = myr[k];
                const int pos = atomicAdd(&hist[r >> SB_SH], 1);
                lsort[pos] = make_int2((int)(((unsigned)r << 16) | (unsigned)cols[e]),
                                       __float_as_int(vals[e]));
            }
        }
        __syncthreads();

        {
            const int4* src = (const int4*)lsort;
            int4* dst = (int4*)(cbuf + (size_t)blk * EPB_S);
            for (int i = t; i < EPB_S / 2; i += 512) dst[i] = src[i];
        }
        if (t < NSB)  cstartarr[blk * 50 + t]   = cstart[t];
        if (t == NSB) cstartarr[blk * 50 + NSB] = EPB_S;
        return;
    }

    // ================= gemm role: ALL 8 WAVES active =================
    f16x8* wt8h = (f16x8*)smem;                    // 32 KB half-W frag
    f16x8* xs8  = (f16x8*)(smem + 32768);          // 16 KB x double-buffer
    const int lane = t & 63;
    const int wv   = t >> 6;                       // 0..7, owns rows wv*16..+15
    const int row0 = (bid - SCAT_BLOCKS) * BM;

    const int srow = t >> 2;                       // 0..127
    const int skg  = t & 3;                        // k-group (8 floats) in step
    const int grow = row0 + srow;
    const bool rv  = grow < N_NODES;
    const float* xp = x + (size_t)(rv ? grow : 0) * IN_DIM + skg * 8;

    float4 xr[2];
    xr[0] = rv ? ((const float4*)xp)[0] : make_float4(0.f, 0.f, 0.f, 0.f);
    xr[1] = rv ? ((const float4*)xp)[1] : make_float4(0.f, 0.f, 0.f, 0.f);
    {
        f16x8 v;
        v[0]=(_Float16)xr[0].x; v[1]=(_Float16)xr[0].y; v[2]=(_Float16)xr[0].z; v[3]=(_Float16)xr[0].w;
        v[4]=(_Float16)xr[1].x; v[5]=(_Float16)xr[1].y; v[6]=(_Float16)xr[1].z; v[7]=(_Float16)xr[1].w;
        xs8[(0 * 4 + skg) * 128 + srow] = v;
    }
    __syncthreads();

    f32x4 acc[8];
#pragma unroll
    for (int nf = 0; nf < 8; ++nf) acc[nf] = (f32x4){0.f, 0.f, 0.f, 0.f};

    const int kg  = lane >> 4;
    const int l15 = lane & 15;
    const int mb  = (wv << 4) + l15;               // this wave's row

#pragma unroll
    for (int H = 0; H < 2; ++H) {
        // stage W half H with all 512 threads (4 iters)
#pragma unroll
        for (int itr = 0; itr < 4; ++itr) {
            const int e  = itr * 4096 + t * 8;
            const int kl = e >> 7;
            const int n0 = e & 127;
            const float4 a4 = *(const float4*)(w + (size_t)((H << 7) + kl) * 128 + n0);
            const float4 b4 = *(const float4*)(w + (size_t)((H << 7) + kl) * 128 + n0 + 4);
            __half* d = (__half*)wt8h + (size_t)(((kl >> 3) << 7) + n0) * 8 + (kl & 7);
            d[0]  = __float2half(a4.x);
            d[8]  = __float2half(a4.y);
            d[16] = __float2half(a4.z);
            d[24] = __float2half(a4.w);
            d[32] = __float2half(b4.x);
            d[40] = __float2half(b4.y);
            d[48] = __float2half(b4.z);
            d[56] = __float2half(b4.w);
        }
        __syncthreads();

#pragma unroll
        for (int ksl = 0; ksl < 4; ++ksl) {
            const int ks  = H * 4 + ksl;
            const int cur = ks & 1;
            if (ks < 7) {
                xr[0] = rv ? ((const float4*)(xp + (ks + 1) * 32))[0] : make_float4(0.f, 0.f, 0.f, 0.f);
                xr[1] = rv ? ((const float4*)(xp + (ks + 1) * 32))[1] : make_float4(0.f, 0.f, 0.f, 0.f);
            }
            {
                const f16x8 b0 = xs8[(cur * 4 + kg) * 128 + mb];
                const int abase = ((ksl * 4 + kg) << 7) + l15;
#pragma unroll
                for (int nf = 0; nf < 8; ++nf) {
                    const f16x8 a = wt8h[abase + (nf << 4)];
                    acc[nf] = __builtin_amdgcn_mfma_f32_16x16x32_f16(a, b0, acc[nf], 0, 0, 0);
                }
            }
            if (ks < 7) {
                f16x8 v;
                v[0]=(_Float16)xr[0].x; v[1]=(_Float16)xr[0].y; v[2]=(_Float16)xr[0].z; v[3]=(_Float16)xr[0].w;
                v[4]=(_Float16)xr[1].x; v[5]=(_Float16)xr[1].y; v[6]=(_Float16)xr[1].z; v[7]=(_Float16)xr[1].w;
                xs8[((cur ^ 1) * 4 + skg) * 128 + srow] = v;
            }
            __syncthreads();
        }
    }

    {
        const int rg = lane >> 4;
        const int m  = row0 + (wv << 4) + l15;
        if (m < N_NODES) {
            __half* hp = h + (size_t)m * OUT_DIM + (rg << 2);
#pragma unroll
            for (int nf = 0; nf < 8; ++nf) {
                union { ushort4 u; __half f[4]; } o;
                o.f[0] = __float2half(acc[nf][0]);
                o.f[1] = __float2half(acc[nf][1]);
                o.f[2] = __float2half(acc[nf][2]);
                o.f[3] = __float2half(acc[nf][3]);
                *(ushort4*)(hp + (nf << 4)) = o.u;
            }
        }
    }
}

// ---------------------------------------------------------------------------
// Dispatch 2: fine scatter (unchanged round-11). NPART=16 -> 784 blocks.
// Block (sb,p) reads 16 dense source runs (L2-hot), LDS counting sort by
// 64 fine bins (fb = key bits 20..25, positional), dense coalesced slab
// write + per-(bin,part) start/count tables.
// ---------------------------------------------------------------------------
__global__ __launch_bounds__(512) void scatter_fine(const int* __restrict__ cstartarr,
                                                    int* __restrict__ fs,
                                                    int* __restrict__ fc,
                                                    int* __restrict__ ovfcnt,
                                                    const int2* __restrict__ cbuf,
                                                    int2* __restrict__ ebuf,
                                                    int2* __restrict__ ovfbuf) {
    __shared__ int2 lsort[ECAP];           // 20.5 KB
    __shared__ int  hist[64], cstart[64], fcv[64];
    __shared__ int  scnt[16], sstart[16];
    __shared__ int  stot;

    const int t    = threadIdx.x;
    const int lane = t & 63;
    const int wv   = t >> 6;               // 0..7, owns 2 source runs
    const int sb   = blockIdx.x / NPART;
    const int p    = blockIdx.x % NPART;

    if (t < 16) {
        const int blk = p * 16 + t;
        const int s0 = cstartarr[blk * 50 + sb];
        const int s1 = cstartarr[blk * 50 + sb + 1];
        scnt[t]   = s1 - s0;
        sstart[t] = blk * EPB_S + s0;
    }
    if (t < 64) hist[t] = 0;
    __syncthreads();

    for (int j = 0; j < 2; ++j) {
        const int s = (wv << 1) | j;
        const int c = scnt[s];
        const int base = sstart[s];
        for (int i = lane; i < c; i += 64)
            atomicAdd(&hist[((unsigned)cbuf[base + i].x >> 20) & 63], 1);
    }
    __syncthreads();

    if (t < 64) {
        const int v = hist[t];
        int s = v;
#pragma unroll
        for (int off = 1; off < 64; off <<= 1) {
            const int u = __shfl_up(s, off);
            if (t >= off) s += u;
        }
        if (t == 63) stot = s;
        cstart[t] = s - v;
        hist[t]   = s - v;
    }
    __syncthreads();

    for (int j = 0; j < 2; ++j) {
        const int s = (wv << 1) | j;
        const int c = scnt[s];
        const int base = sstart[s];
        for (int i = lane; i < c; i += 64) {
            const int2 rc = cbuf[base + i];
            const int fb = ((unsigned)rc.x >> 20) & 63;
            const int pos = atomicAdd(&hist[fb], 1);
            if (pos < ECAP) {
                lsort[pos] = rc;
            } else {
                const int q = atomicAdd(ovfcnt, 1);      // statistically unreachable
                if (q < OVF_CAP) ovfbuf[q] = rc;
            }
        }
    }
    __syncthreads();

    if (t < 64) {
        int c = hist[t] - cstart[t];
        if (c > SEGP) c = SEGP;
        if (cstart[t] + c > ECAP) c = (cstart[t] < ECAP) ? (ECAP - cstart[t]) : 0;
        fcv[t] = c;
        fs[(sb * 64 + t) * NPART + p] = cstart[t];
        fc[(sb * 64 + t) * NPART + p] = c;
    }
    __syncthreads();

    const int tot = min(stot, ECAP);
    int2* dst = ebuf + (size_t)(sb * NPART + p) * ECAP;
    for (int i = t; i < tot; i += 512) {
        const int2 rc = lsort[i];
        dst[i] = rc;
        const int fb  = ((unsigned)rc.x >> 20) & 63;
        const int off = i - cstart[fb];
        if (off >= fcv[fb]) {                            // statistically unreachable
            const int q = atomicAdd(ovfcnt, 1);
            if (q < OVF_CAP) ovfbuf[q] = rc;
        }
    }
}

// ---------------------------------------------------------------------------
// Dispatch 3: FUSED sort+gather (unchanged round-11: 54.7 us, 53% occ).
// 16-row bins, 3136 blocks x 256 thr, srec-only 12 KB LDS.
// Sort class = lrow<<4 | col>>12.
// ---------------------------------------------------------------------------
#define NCLS 256

__global__ __launch_bounds__(256) void sort_gather(const int* __restrict__ fs,
                                                   const int* __restrict__ fc,
                                                   const int* __restrict__ ovfcnt,
                                                   const int2* __restrict__ ebuf,
                                                   const int2* __restrict__ ovfbuf,
                                                   const __half* __restrict__ h,
                                                   float* __restrict__ out) {
    __shared__ int2 srec[CAPG];            // 12 KB sorted records
    __shared__ int  hist[NCLS];
    __shared__ int  pfx[NCLS];
    __shared__ int  rowoff_l[BIN_ROWS + 1];
    __shared__ int  wsum[4];
    __shared__ int  poff[NPART + 1];
    __shared__ int  fsrt[NPART];

    const int t    = threadIdx.x;          // 0..255
    const int bin  = blockIdx.x;
    const int wv   = t >> 6;               // 0..3
    const int lane = t & 63;
    const int sb   = bin >> 6;

    hist[t] = 0;
    if (t < NPART) fsrt[t] = fs[bin * NPART + t];
    if (t == 0) {
        int a = 0;
        poff[0] = 0;
#pragma unroll
        for (int p = 0; p < NPART; ++p) { a += fc[bin * NPART + p]; poff[p + 1] = a; }
    }
    __syncthreads();
    const int cnt = poff[NPART];

#pragma unroll
    for (int j = 0; j < 4; ++j) {
        const int p  = (wv << 2) + j;
        const int cp = poff[p + 1] - poff[p];
        const int2* src = ebuf + (size_t)(sb * NPART + p) * ECAP + fsrt[p];
        for (int i = lane; i < cp; i += 64) {
            const int k = src[i].x;
            atomicAdd(&hist[(((k >> 16) & 15) << 4) | ((k & 0xFFFF) >> 12)], 1);
        }
    }
    __syncthreads();

    {
        const int v = hist[t];
        int s = v;
#pragma unroll
        for (int off = 1; off < 64; off <<= 1) {
            const int u = __shfl_up(s, off);
            if (lane >= off) s += u;
        }
        if (lane == 63) wsum[wv] = s;
        __syncthreads();
        if (t == 0) {
            int a = 0;
#pragma unroll
            for (int i = 0; i < 4; ++i) { const int c = wsum[i]; wsum[i] = a; a += c; }
        }
        __syncthreads();
        const int incl = s + wsum[wv];
        pfx[t]  = incl;
        hist[t] = incl - v;
    }
    __syncthreads();
    if (t < BIN_ROWS) rowoff_l[t] = t ? pfx[(t << 4) - 1] : 0;
    if (t == BIN_ROWS) rowoff_l[BIN_ROWS] = cnt;
    __syncthreads();

#pragma unroll
    for (int j = 0; j < 4; ++j) {
        const int p  = (wv << 2) + j;
        const int cp = poff[p + 1] - poff[p];
        const int2* src = ebuf + (size_t)(sb * NPART + p) * ECAP + fsrt[p];
        for (int i = lane; i < cp; i += 64) {
            const int2 r = src[i];
            const int cls = (((r.x >> 16) & 15) << 4) | ((r.x & 0xFFFF) >> 12);
            const int pos = atomicAdd(&hist[cls], 1);
            srec[pos] = r;
        }
    }
    __syncthreads();

    const int grp = lane >> 4;
    const int gl  = lane & 15;
    int novf = *ovfcnt;
    if (novf > OVF_CAP) novf = OVF_CAP;

    for (int pp = 0; pp < 2; ++pp) {
        const int lr0 = (wv << 2) + 2 * pp;
        const int lr1 = lr0 + 1;
        const int b0 = rowoff_l[lr0], e0 = rowoff_l[lr0 + 1];
        const int b1 = rowoff_l[lr1], e1 = rowoff_l[lr1 + 1];
        const int n0 = e0 - b0, n1 = e1 - b1;
        const int nmax = n0 > n1 ? n0 : n1;
        const int iters = (nmax + 3) >> 2;

        f32x8 a0 = (f32x8){0.f,0.f,0.f,0.f,0.f,0.f,0.f,0.f};
        f32x8 a1 = (f32x8){0.f,0.f,0.f,0.f,0.f,0.f,0.f,0.f};

        for (int it = 0; it < iters; ++it) {
            const int i0 = b0 + (it << 2) + grp;
            const int i1 = b1 + (it << 2) + grp;
            const bool v0i = i0 < e0;
            const bool v1i = i1 < e1;
            const int2 rA = srec[v0i ? i0 : 0];
            const int2 rB = srec[v1i ? i1 : 0];
            const float vA = v0i ? __int_as_float(rA.y) : 0.f;
            const float vB = v1i ? __int_as_float(rB.y) : 0.f;
            const f16x8 hA = *(const f16x8*)(h + (size_t)(rA.x & 0xFFFF) * OUT_DIM + (gl << 3));
            const f16x8 hB = *(const f16x8*)(h + (size_t)(rB.x & 0xFFFF) * OUT_DIM + (gl << 3));
#pragma unroll
            for (int j = 0; j < 8; ++j) {
                a0[j] += vA * (float)hA[j];
                a1[j] += vB * (float)hB[j];
            }
        }

        for (int e = 0; e < novf; ++e) {
            const int2 rec = ovfbuf[e];
            const unsigned urow = ((unsigned)rec.x) >> 16;
            if ((int)(urow >> BIN_SH) == bin && grp == 0) {
                const int lr = (int)(urow & (BIN_ROWS - 1));
                if (lr == lr0 || lr == lr1) {
                    const float v = __int_as_float(rec.y);
                    const f16x8 hv = *(const f16x8*)(h + (size_t)(rec.x & 0xFFFF) * OUT_DIM + (gl << 3));
#pragma unroll
                    for (int j = 0; j < 8; ++j) {
                        if (lr == lr0) a0[j] += v * (float)hv[j];
                        else           a1[j] += v * (float)hv[j];
                    }
                }
            }
        }

#pragma unroll
        for (int j = 0; j < 8; ++j) {
            float x0 = a0[j], x1 = a1[j];
            x0 += __shfl_xor(x0, 16); x0 += __shfl_xor(x0, 32);
            x1 += __shfl_xor(x1, 16); x1 += __shfl_xor(x1, 32);
            a0[j] = x0; a1[j] = x1;
        }

        const int lrow = (grp & 2) ? lr1 : lr0;
        const int grow = (bin << BIN_SH) + lrow;
        float q[4];
#pragma unroll
        for (int k = 0; k < 4; ++k) {
            const float lo = (grp & 2) ? a1[k]     : a0[k];
            const float hi = (grp & 2) ? a1[k + 4] : a0[k + 4];
            q[k] = lrelu((grp & 1) ? hi : lo);
        }
        if (grow < N_NODES) {
            float4 o = make_float4(q[0], q[1], q[2], q[3]);
            *(float4*)(out + (size_t)grow * OUT_DIM + (gl << 3) + ((grp & 1) << 2)) = o;
        }
    }
}

// ---------------------------------------------------------------------------
// Launch: 3 dispatches (round-11 structure). prep (coarse || gemm || zero)
// -> scatter_fine -> sort_gather.
// ---------------------------------------------------------------------------
extern "C" void kernel_launch(void* const* d_in, const int* in_sizes, int n_in,
                              void* d_out, int out_size, void* d_ws, size_t ws_size,
                              hipStream_t stream) {
    const float* x    = (const float*)d_in[0];
    const float* w    = (const float*)d_in[1];
    const float* vals = (const float*)d_in[2];
    const int*   rows = (const int*)d_in[3];
    const int*   cols = (const int*)d_in[4];
    float* out = (float*)d_out;

    char* ws = (char*)d_ws;
    size_t off = 0;
    auto alloc = [&](size_t bytes) {
        void* p = ws + off;
        off = (off + bytes + 255) & ~(size_t)255;
        return p;
    };
    int2*   cbuf     = (int2*)  alloc((size_t)N_EDGES * sizeof(int2));               // 12.8 MB
    __half* h        = (__half*)alloc((size_t)N_NODES * OUT_DIM * sizeof(__half));   // 12.8 MB
    int2*   ebuf     = (int2*)  alloc((size_t)NSB * NPART * ECAP * sizeof(int2));    // 16.1 MB
    int2*   ovfbuf   = (int2*)  alloc((size_t)OVF_CAP * sizeof(int2));               // 0.5 MB
    int*    cstartarr= (int*)   alloc((size_t)SCAT_BLOCKS * 50 * sizeof(int));       // 50 KB
    int*    fs       = (int*)   alloc((size_t)NBIN_PAD * NPART * sizeof(int));       // 200 KB
    int*    fc       = (int*)   alloc((size_t)NBIN_PAD * NPART * sizeof(int));       // 200 KB
    int*    ovfcnt   = (int*)   alloc(sizeof(int));

    prep<<<PREP_BLOCKS, 512, 0, stream>>>(rows, cols, vals, x, w,
                                          cstartarr, ovfcnt, cbuf, h);
    scatter_fine<<<NSB * NPART, 512, 0, stream>>>(cstartarr, fs, fc, ovfcnt,
                                                  cbuf, ebuf, ovfbuf);
    sort_gather<<<NBIN_PAD, 256, 0, stream>>>(fs, fc, ovfcnt, ebuf, ovfbuf, h, out);
}